// Round 1
// 484.276 us; speedup vs baseline: 1.0931x; 1.0931x over previous
//
#include <hip/hip_runtime.h>
#include <hip/hip_bf16.h>

// ---------------------------------------------------------------------------
// Fused decoder self-attention. B=16,N=307,T=48,D=128,H=8,DK=16, conv K=3,
// segments (12,12,24). One workgroup (4 waves) per (b,n). Global tensors are
// FLOAT32 (reference dtype); internal compute is bf16 MFMA with f32 accum.
// d_ws holds bf16 weights: conv_q [tap][e][d], conv_k [tap][e][d], vw, ow.
//
// R1: LDS 62KB -> 51.9KB (3 blocks/CU instead of 2) via in-place conv
//     projections (stage buffer == output buffer, barrier between acc and
//     write) + async-stage split (global loads issued a phase early into
//     registers, written to LDS after the intervening compute).
// Buffer plan:
//   shA: V-stage -> (V-proj reads) -> K-stage -> K (in-place)
//   shB: Q-stage -> Q (in-place)   -> X (attention writeback, per-wave safe)
// ---------------------------------------------------------------------------

typedef __attribute__((ext_vector_type(8))) short short8;      // 8 x bf16
typedef __attribute__((ext_vector_type(4))) float floatx4;     // MFMA C/D
typedef __attribute__((ext_vector_type(4))) unsigned short ushortx4;

#define MFMA16(a, b, c) __builtin_amdgcn_mfma_f32_16x16x32_bf16((a), (b), (c), 0, 0, 0)

__device__ __forceinline__ unsigned short f2bf(float x) {
  __hip_bfloat16 h = __float2bfloat16(x);
  return __builtin_bit_cast(unsigned short, h);
}

// padded-row map: 2 zero rows before each segment (segments at t=0,12,24)
__device__ __forceinline__ int prow(int t) {
  return t + 2 + (t >= 12 ? 2 : 0) + (t >= 24 ? 2 : 0);
}

__device__ __forceinline__ short8 lds8(const __hip_bfloat16* p) {
  return *(const short8*)p;
}

// ---- weight prep: conv (e,d,1,tap) f32 -> [tap][e][d] bf16; vw/ow f32->bf16
__global__ void prep_weights(const float* __restrict__ wq,
                             const float* __restrict__ wk,
                             const float* __restrict__ vw,
                             const float* __restrict__ ow,
                             __hip_bfloat16* __restrict__ dst) {
  int i = blockIdx.x * 256 + threadIdx.x;          // 0..131071
  float v;
  if (i < 98304) {                                 // two conv transforms
    int which = i / 49152;
    int r = i % 49152;
    int tap = r / 16384;
    int rr = r & 16383;
    int e = rr >> 7, d = rr & 127;
    const float* src = which ? wk : wq;
    v = src[e * 384 + d * 3 + tap];
  } else {
    int r = i - 98304;
    int j = r & 16383;
    v = (r >> 14) ? ow[j] : vw[j];
  }
  dst[i] = __float2bfloat16(v);
}

// ---------------------------------------------------------------------------
constexpr int XS = 136;   // row stride for shA/shB (padded 54-row tiles)
constexpr int VS = 56;    // sh_vt row stride
constexpr int WQ_OFF = 0;
constexpr int WK_OFF = 49152;
constexpr int VW_OFF = 98304;
constexpr int OW_OFF = 114688;

// T14 split staging: issue global loads early ...
__device__ __forceinline__ void stage_load(const float* __restrict__ src,
                                           float4* r, int tid) {
  const float4* g = (const float4*)src;            // 48*128 f32 = 1536 x 16B
  #pragma unroll
  for (int it = 0; it < 6; ++it) r[it] = g[tid + it * 256];
}

// ... and convert/write to LDS late (under the previous compute phase).
__device__ __forceinline__ void stage_write(const float4* r,
                                            __hip_bfloat16* sh, int tid) {
  #pragma unroll
  for (int it = 0; it < 6; ++it) {
    int c = tid + it * 256;                        // chunk of 4 floats
    int t = c >> 5;                                // 32 chunks / row
    int col = (c & 31) * 4;
    float4 f = r[it];
    ushortx4 pk;
    pk[0] = f2bf(f.x); pk[1] = f2bf(f.y); pk[2] = f2bf(f.z); pk[3] = f2bf(f.w);
    *(ushortx4*)&sh[prow(t) * XS + col] = pk;
  }
}

// causal 3-tap conv: acc[t][e] = sum_tap x[t-(2-tap)] . W_tap[e,:]
__device__ __forceinline__ void conv_acc(const __hip_bfloat16* shx,
                                         const __hip_bfloat16* __restrict__ wt,
                                         floatx4 acc[3][2],
                                         int wv, int quad, int l16) {
  const int e0 = (wv * 2) * 16 + l16;
  const int e1 = (wv * 2 + 1) * 16 + l16;
  #pragma unroll
  for (int tap = 0; tap < 3; ++tap) {
    const __hip_bfloat16* W = wt + tap * 16384;    // [e][d]
    const int sh = 2 - tap;
    #pragma unroll
    for (int ks = 0; ks < 4; ++ks) {
      int k0 = ks * 32 + quad * 8;
      short8 b0 = lds8(W + e0 * 128 + k0);
      short8 b1 = lds8(W + e1 * 128 + k0);
      #pragma unroll
      for (int mi = 0; mi < 3; ++mi) {
        int t = mi * 16 + l16;
        short8 a = lds8(&shx[(prow(t) - sh) * XS + k0]);
        acc[mi][0] = MFMA16(a, b0, acc[mi][0]);
        acc[mi][1] = MFMA16(a, b1, acc[mi][1]);
      }
    }
  }
}

// write conv result (+bias) as bf16 rows 0..47 (compact, stride XS) — may be
// the SAME buffer conv_acc read from, provided a barrier sits between.
__device__ __forceinline__ void conv_write(floatx4 acc[3][2],
                                           const float* __restrict__ bias,
                                           __hip_bfloat16* dst,
                                           int wv, int quad, int l16) {
  #pragma unroll
  for (int nti = 0; nti < 2; ++nti) {
    int e = (wv * 2 + nti) * 16 + l16;
    float bb = bias[e];
    #pragma unroll
    for (int mi = 0; mi < 3; ++mi) {
      int t0 = mi * 16 + quad * 4;
      #pragma unroll
      for (int r = 0; r < 4; ++r)
        dst[(t0 + r) * XS + e] = __float2bfloat16(acc[mi][nti][r] + bb);
    }
  }
}

__global__ __launch_bounds__(256, 3) void fused_attn(
    const float* __restrict__ gq, const float* __restrict__ gk,
    const float* __restrict__ gv,
    const __hip_bfloat16* __restrict__ wts,        // d_ws bf16 weights
    const float* __restrict__ cqb, const float* __restrict__ ckb,
    const float* __restrict__ vb, const float* __restrict__ ob,
    float* __restrict__ out) {
  __shared__ __align__(16) __hip_bfloat16 shA[54 * XS];       // V-stage/K
  __shared__ __align__(16) __hip_bfloat16 shB[54 * XS];       // Q-stage/Q/X
  __shared__ __align__(16) __hip_bfloat16 sh_vt[128 * VS];    // V^T [e][t]
  __shared__ __align__(16) __hip_bfloat16 sh_p[4 * 16 * 64];  // per-wave P

  const int tid  = threadIdx.x;
  const int wv   = tid >> 6;
  const int lane = tid & 63;
  const int quad = lane >> 4;
  const int l16  = lane & 15;
  const long base = (long)blockIdx.x * (48 * 128);

  const __hip_bfloat16* wq_t = wts + WQ_OFF;
  const __hip_bfloat16* wk_t = wts + WK_OFF;
  const __hip_bfloat16* vw   = wts + VW_OFF;
  const __hip_bfloat16* ow   = wts + OW_OFF;

  // zero segment-pad rows {0,1,14,15,28,29} of BOTH buffers (never re-staged)
  if (tid < 204) {
    int b = tid >= 102;
    int i = b ? tid - 102 : tid;
    int pr = i / 17, pc = i % 17;
    int row = (pr >> 1) * 14 + (pr & 1);
    uint4 z = {0, 0, 0, 0};
    __hip_bfloat16* s = b ? shB : shA;
    *(uint4*)&s[row * XS + pc * 8] = z;
  }

  const int e0 = (wv * 2) * 16 + l16;
  const int e1 = (wv * 2 + 1) * 16 + l16;

  // ---- stage V into A; issue Q loads early
  float4 rv[6];
  stage_load(gv + base, rv, tid);
  stage_write(rv, shA, tid);
  float4 rq[6];
  stage_load(gq + base, rq, tid);
  __syncthreads();                                 // s1: A = V staged

  // ================= V projection (accumulate; reads A) =================
  floatx4 vacc[3][2] = {};
  #pragma unroll
  for (int ks = 0; ks < 4; ++ks) {
    int k0 = ks * 32 + quad * 8;
    short8 b0 = lds8(vw + e0 * 128 + k0);
    short8 b1 = lds8(vw + e1 * 128 + k0);
    #pragma unroll
    for (int mi = 0; mi < 3; ++mi) {
      int t = mi * 16 + l16;
      short8 a = lds8(&shA[prow(t) * XS + k0]);
      vacc[mi][0] = MFMA16(a, b0, vacc[mi][0]);
      vacc[mi][1] = MFMA16(a, b1, vacc[mi][1]);
    }
  }
  stage_write(rq, shB, tid);                       // Q -> B (B unread so far)
  float4 rk[6];
  stage_load(gk + base, rk, tid);                  // issue K loads early
  __syncthreads();                                 // s2: B = Q staged; A reads done

  // V^T write (transposed, 8B stores)
  #pragma unroll
  for (int nti = 0; nti < 2; ++nti) {
    int e = (wv * 2 + nti) * 16 + l16;
    float bv = vb[e];
    #pragma unroll
    for (int mi = 0; mi < 3; ++mi) {
      int t0 = mi * 16 + quad * 4;
      ushortx4 pk;
      #pragma unroll
      for (int r = 0; r < 4; ++r) pk[r] = f2bf(vacc[mi][nti][r] + bv);
      *(ushortx4*)&sh_vt[e * VS + t0] = pk;
    }
  }

  // ================= Q conv (accumulate; reads B) =================
  floatx4 qacc[3][2] = {};
  conv_acc(shB, wq_t, qacc, wv, quad, l16);
  stage_write(rk, shA, tid);                       // K -> A (A free after s2)
  __syncthreads();                                 // s3: A = K staged; B reads done

  conv_write(qacc, cqb, shB, wv, quad, l16);       // Q in-place into B

  // ================= K conv (accumulate; reads A) =================
  floatx4 kacc[3][2] = {};
  conv_acc(shA, wk_t, kacc, wv, quad, l16);
  __syncthreads();                                 // s4: B = Q ready; A reads done

  conv_write(kacc, ckb, shA, wv, quad, l16);       // K in-place into A
  __syncthreads();                                 // s5: A = K ready

  // ================= attention: 2 heads per wave (Q=shB, K=shA) ==========
  {
    __hip_bfloat16* shp = sh_p + wv * (16 * 64);
    // zero P pad cols 48..63 (swizzled chunks 6,7 of every row)
    if (lane < 32) {
      int lt = lane >> 1;
      int cp = (6 + (lane & 1)) ^ (lt & 7);
      uint4 z = {0, 0, 0, 0};
      *(uint4*)&shp[lt * 64 + cp * 8] = z;
    }
    short8 zf = {0, 0, 0, 0, 0, 0, 0, 0};
    #pragma unroll
    for (int hi = 0; hi < 2; ++hi) {
      const int hq = (wv * 2 + hi) * 16;
      #pragma unroll
      for (int mi = 0; mi < 3; ++mi) {
        // ---- S row-tile = Q_h[mi] K_h^T  (K=16 padded to 32: quads 2,3 zero)
        floatx4 s0 = {}, s1 = {}, s2 = {};
        short8 aq  = (quad < 2) ? lds8(&shB[(mi * 16 + l16) * XS + hq + quad * 8]) : zf;
        short8 bk0 = (quad < 2) ? lds8(&shA[(l16) * XS + hq + quad * 8]) : zf;
        short8 bk1 = (quad < 2) ? lds8(&shA[(16 + l16) * XS + hq + quad * 8]) : zf;
        short8 bk2 = (quad < 2) ? lds8(&shA[(32 + l16) * XS + hq + quad * 8]) : zf;
        s0 = MFMA16(aq, bk0, s0);
        s1 = MFMA16(aq, bk1, s1);
        s2 = MFMA16(aq, bk2, s2);
        // ---- causal mask + row softmax (rows in C layout: quad*4+r)
        const int tb = mi * 16 + quad * 4;
        #pragma unroll
        for (int r = 0; r < 4; ++r) {
          int t = tb + r;
          float v0 = (l16 <= t)      ? s0[r] * 0.25f : -1e30f;
          float v1 = (16 + l16 <= t) ? s1[r] * 0.25f : -1e30f;
          float v2 = (32 + l16 <= t) ? s2[r] * 0.25f : -1e30f;
          float mx = fmaxf(v0, fmaxf(v1, v2));
          #pragma unroll
          for (int d = 1; d < 16; d <<= 1) mx = fmaxf(mx, __shfl_xor(mx, d, 64));
          float p0 = __expf(v0 - mx), p1 = __expf(v1 - mx), p2 = __expf(v2 - mx);
          float sm = p0 + p1 + p2;
          #pragma unroll
          for (int d = 1; d < 16; d <<= 1) sm += __shfl_xor(sm, d, 64);
          float inv = __builtin_amdgcn_rcpf(sm);
          int lt = quad * 4 + r;
          int xr = lt & 7, lo = l16 & 7, hi8 = l16 >> 3, rowb = lt * 64;
          shp[rowb + (((0 + hi8) ^ xr) << 3) + lo] = __float2bfloat16(p0 * inv);
          shp[rowb + (((2 + hi8) ^ xr) << 3) + lo] = __float2bfloat16(p1 * inv);
          shp[rowb + (((4 + hi8) ^ xr) << 3) + lo] = __float2bfloat16(p2 * inv);
        }
        // ---- X[mi] = P V_h  (K=48 padded to 64)
        floatx4 x = {};
        #pragma unroll
        for (int ks = 0; ks < 2; ++ks) {
          int c = (ks * 4 + quad) ^ (l16 & 7);
          short8 ap = lds8(&shp[l16 * 64 + c * 8]);
          int sb = ks * 32 + quad * 8;
          short8 bvv = (sb < 48) ? lds8(&sh_vt[(hq + l16) * VS + sb]) : zf;
          x = MFMA16(ap, bvv, x);
        }
        // X writeback into B (per-wave column slice; read-before-write within
        // this wave's program order — safe without extra barriers)
        #pragma unroll
        for (int r = 0; r < 4; ++r)
          shB[(tb + r) * XS + hq + l16] = __float2bfloat16(x[r]);
      }
    }
  }
  __syncthreads();                                 // s6: X ready in B

  // ================= output projection + f32 store =================
  {
    floatx4 acc[3][2] = {};
    #pragma unroll
    for (int ks = 0; ks < 4; ++ks) {
      int k0 = ks * 32 + quad * 8;
      short8 b0 = lds8(ow + e0 * 128 + k0);
      short8 b1 = lds8(ow + e1 * 128 + k0);
      #pragma unroll
      for (int mi = 0; mi < 3; ++mi) {
        short8 a = lds8(&shB[(mi * 16 + l16) * XS + k0]);
        acc[mi][0] = MFMA16(a, b0, acc[mi][0]);
        acc[mi][1] = MFMA16(a, b1, acc[mi][1]);
      }
    }
    float* op = out + base;
    #pragma unroll
    for (int nti = 0; nti < 2; ++nti) {
      int e = (wv * 2 + nti) * 16 + l16;
      float bo = ob[e];
      #pragma unroll
      for (int mi = 0; mi < 3; ++mi) {
        int t0 = mi * 16 + quad * 4;
        #pragma unroll
        for (int r = 0; r < 4; ++r)
          op[(t0 + r) * 128 + e] = acc[mi][nti][r] + bo;
      }
    }
  }
}

extern "C" void kernel_launch(void* const* d_in, const int* in_sizes, int n_in,
                              void* d_out, int out_size, void* d_ws, size_t ws_size,
                              hipStream_t stream) {
  (void)in_sizes; (void)n_in; (void)out_size; (void)ws_size;
  const float* query = (const float*)d_in[0];
  const float* key   = (const float*)d_in[1];
  const float* value = (const float*)d_in[2];
  // d_in[3] = mask: deterministic causal tril -> applied analytically
  const float* cqw = (const float*)d_in[4];
  const float* cqb = (const float*)d_in[5];
  const float* ckw = (const float*)d_in[6];
  const float* ckb = (const float*)d_in[7];
  const float* vw  = (const float*)d_in[8];
  const float* vb  = (const float*)d_in[9];
  const float* ow  = (const float*)d_in[10];
  const float* ob  = (const float*)d_in[11];

  __hip_bfloat16* wts = (__hip_bfloat16*)d_ws;     // 131072 bf16 = 256 KiB

  prep_weights<<<dim3(512), 256, 0, stream>>>(cqw, ckw, vw, ow, wts);
  fused_attn<<<dim3(16 * 307), 256, 0, stream>>>(
      query, key, value, wts, cqb, ckb, vb, ob, (float*)d_out);
}